// Round 1
// baseline (426.381 us; speedup 1.0000x reference)
//
#include <hip/hip_runtime.h>
#include <hip/hip_bf16.h>

// Problem constants (from reference): B=2, T=10000, M=100000, D=64
#define NB 2
#define NT 10000
#define NM 100000
#define ND 64
#define ROWS1 (NB * NT * 2)   // 40000 x_1st rows
#define ROWS2 (NB * NM * 4)   // 800000 x_2nd/out rows

typedef __attribute__((ext_vector_type(4))) float f32x4;
typedef __attribute__((ext_vector_type(8))) short s16x8;   // 8 bf16 (4 VGPRs) MFMA frag

// fp32 -> bf16 round-to-nearest-even (data is well-behaved normals; no NaN path)
static __device__ __forceinline__ unsigned short f2bf(float f) {
    union { float f; unsigned int u; } v; v.f = f;
    unsigned int u = v.u;
    u += 0x7fffu + ((u >> 16) & 1u);
    return (unsigned short)(u >> 16);
}

static __device__ __forceinline__ s16x8 pack8(f32x4 a, f32x4 b) {
    s16x8 r;
    r[0] = (short)f2bf(a[0]); r[1] = (short)f2bf(a[1]);
    r[2] = (short)f2bf(a[2]); r[3] = (short)f2bf(a[3]);
    r[4] = (short)f2bf(b[0]); r[5] = (short)f2bf(b[1]);
    r[6] = (short)f2bf(b[2]); r[7] = (short)f2bf(b[3]);
    return r;
}

// ---------------------------------------------------------------------------
// k0: Wc = We·Wm (bf16), We -> bf16, bc = We·bm + be (fp32). 1 block, 256 thr.
// ---------------------------------------------------------------------------
__global__ void k0_prep(const float* __restrict__ Wm, const float* __restrict__ bm,
                        const float* __restrict__ We, const float* __restrict__ be,
                        float* __restrict__ bc,
                        unsigned short* __restrict__ Wc_bf,
                        unsigned short* __restrict__ We_bf) {
    const int tid = threadIdx.x;            // 0..255
    const int o = tid >> 2;                 // 0..63
    const int dbase = (tid & 3) << 4;       // 0,16,32,48
    for (int d = dbase; d < dbase + 16; ++d) {
        float acc = 0.f;
        for (int e = 0; e < 64; ++e) acc += We[o * 64 + e] * Wm[e * 64 + d];
        Wc_bf[o * 64 + d] = f2bf(acc);
        We_bf[o * 64 + d] = f2bf(We[o * 64 + d]);
    }
    if (tid < 64) {
        float acc = be[tid];
        for (int e = 0; e < 64; ++e) acc += We[tid * 64 + e] * bm[e];
        bc[tid] = acc;
    }
}

// ---------------------------------------------------------------------------
// k1: G[row] = Wc·x1[row] + 0.5*bc   for the 40000 x_1st rows.
// One wave per 16 rows. MFMA 16x16x32 bf16: A=Wc tile, B=x1 rows.
// ---------------------------------------------------------------------------
__global__ __launch_bounds__(256) void k1_G(const float* __restrict__ x1,
        const unsigned short* __restrict__ Wc_bf, const float* __restrict__ bc,
        float* __restrict__ G) {
    const int lane = threadIdx.x & 63;
    const int wt = blockIdx.x * 4 + (threadIdx.x >> 6);
    const int rowbase = wt * 16;
    const int i = lane & 15;    // A-row (o within 16-tile) AND B-col (x1 row within tile)
    const int kg = lane >> 4;   // k-group

    // B fragments: x1 rows, k = kh*32 + kg*8 + {0..7}
    const float* xr = x1 + (size_t)(rowbase + i) * 64 + kg * 8;
    const s16x8 b0 = pack8(*(const f32x4*)(xr),      *(const f32x4*)(xr + 4));
    const s16x8 b1 = pack8(*(const f32x4*)(xr + 32), *(const f32x4*)(xr + 36));

    f32x4 acc[4];
#pragma unroll
    for (int t = 0; t < 4; ++t) acc[t] = (f32x4){0.f, 0.f, 0.f, 0.f};

#pragma unroll
    for (int t = 0; t < 4; ++t) {
        const unsigned short* wr = Wc_bf + (t * 16 + i) * 64 + kg * 8;
        const s16x8 a0 = *(const s16x8*)(wr);
        const s16x8 a1 = *(const s16x8*)(wr + 32);
        acc[t] = __builtin_amdgcn_mfma_f32_16x16x32_bf16(a0, b0, acc[t], 0, 0, 0);
        acc[t] = __builtin_amdgcn_mfma_f32_16x16x32_bf16(a1, b1, acc[t], 0, 0, 0);
    }

    // D layout: col=lane&15 (row of x1), row=(lane>>4)*4+reg (output o within tile)
    float* grow = G + (size_t)(rowbase + i) * 64;
#pragma unroll
    for (int t = 0; t < 4; ++t) {
        const int o = t * 16 + kg * 4;
        const f32x4 bcv = *(const f32x4*)(bc + o);
        f32x4 v;
#pragma unroll
        for (int r = 0; r < 4; ++r) v[r] = acc[t][r] + 0.5f * bcv[r];
        *(f32x4*)(grow + o) = v;
    }
}

// ---------------------------------------------------------------------------
// k2: out[row] = We·x2[row] + G[b,e0,I(c)] + G[b,e1,J(c)]   (bias inside G)
// One wave per 16 rows (= 4 edges x 4 channels). 8 MFMA per wave.
// ---------------------------------------------------------------------------
__global__ __launch_bounds__(256) void k2_main(const float* __restrict__ x2,
        const unsigned short* __restrict__ We_bf, const int* __restrict__ edge,
        const float* __restrict__ G, float* __restrict__ out) {
    const int lane = threadIdx.x & 63;
    const int wt = blockIdx.x * 4 + (threadIdx.x >> 6);
    const long rowbase = (long)wt * 16;
    const int i = lane & 15;
    const int kg = lane >> 4;

    // A fragments: We tiles (bf16, pre-converted; L1-hot)
    s16x8 a[4][2];
#pragma unroll
    for (int t = 0; t < 4; ++t) {
        const unsigned short* wr = We_bf + (t * 16 + i) * 64 + kg * 8;
        a[t][0] = *(const s16x8*)(wr);
        a[t][1] = *(const s16x8*)(wr + 32);
    }

    // B fragments: 16 rows of x2
    const float* xr = x2 + (rowbase + i) * 64 + kg * 8;
    const s16x8 b0 = pack8(*(const f32x4*)(xr),      *(const f32x4*)(xr + 4));
    const s16x8 b1 = pack8(*(const f32x4*)(xr + 32), *(const f32x4*)(xr + 36));

    f32x4 acc[4];
#pragma unroll
    for (int t = 0; t < 4; ++t) acc[t] = (f32x4){0.f, 0.f, 0.f, 0.f};
#pragma unroll
    for (int t = 0; t < 4; ++t) {
        acc[t] = __builtin_amdgcn_mfma_f32_16x16x32_bf16(a[t][0], b0, acc[t], 0, 0, 0);
        acc[t] = __builtin_amdgcn_mfma_f32_16x16x32_bf16(a[t][1], b1, acc[t], 0, 0, 0);
    }

    // Epilogue: each lane owns one full output row (gr), o-slices of 4 per tile t.
    const long gr = rowbase + i;                 // global row in (B,M,4)
    const int b = (int)(gr / (NM * 4));
    const int mc = (int)(gr - (long)b * (NM * 4));
    const int m = mc >> 2;
    const int c = mc & 3;                        // channel: I=c>>1, J=c&1
    const int e0 = edge[m];
    const int e1 = edge[NM + m];
    const float* Gi = G + (((size_t)b * NT + e0) * 2 + (c >> 1)) * 64;
    const float* Gj = G + (((size_t)b * NT + e1) * 2 + (c & 1)) * 64;
    float* orow = out + gr * 64;
#pragma unroll
    for (int t = 0; t < 4; ++t) {
        const int o = t * 16 + kg * 4;
        const f32x4 gi = *(const f32x4*)(Gi + o);
        const f32x4 gj = *(const f32x4*)(Gj + o);
        f32x4 v;
#pragma unroll
        for (int r = 0; r < 4; ++r) v[r] = acc[t][r] + gi[r] + gj[r];
        *(f32x4*)(orow + o) = v;
    }
}

// ---------------------------------------------------------------------------
extern "C" void kernel_launch(void* const* d_in, const int* in_sizes, int n_in,
                              void* d_out, int out_size, void* d_ws, size_t ws_size,
                              hipStream_t stream) {
    const float* x1 = (const float*)d_in[0];   // (B,T,2,D)
    const float* x2 = (const float*)d_in[1];   // (B,M,4,D)
    const float* Wm = (const float*)d_in[2];   // (D,D)
    const float* bm = (const float*)d_in[3];   // (D,)
    const float* We = (const float*)d_in[4];   // (D,D)
    const float* be = (const float*)d_in[5];   // (D,)
    const int* edge = (const int*)d_in[6];     // (2,M)
    float* out = (float*)d_out;

    // Workspace layout: G (40000*64 f32) | bc (64 f32) | Wc_bf (4096 u16) | We_bf (4096 u16)
    float* G = (float*)d_ws;
    float* bc = G + (size_t)ROWS1 * 64;                      // offset 2,560,000 floats
    unsigned short* Wc_bf = (unsigned short*)(bc + 64);      // 16B-aligned
    unsigned short* We_bf = Wc_bf + 64 * 64;

    k0_prep<<<1, 256, 0, stream>>>(Wm, bm, We, be, bc, Wc_bf, We_bf);
    k1_G<<<ROWS1 / 16 / 4, 256, 0, stream>>>(x1, Wc_bf, bc, G);        // 625 blocks
    k2_main<<<ROWS2 / 16 / 4, 256, 0, stream>>>(x2, We_bf, edge, G, out); // 12500 blocks
}

// Round 2
// 388.222 us; speedup vs baseline: 1.0983x; 1.0983x over previous
//
#include <hip/hip_runtime.h>
#include <hip/hip_bf16.h>

// Problem constants (from reference): B=2, T=10000, M=100000, D=64
#define NB 2
#define NT 10000
#define NM 100000
#define ND 64
#define ROWS1 (NB * NT * 2)   // 40000 x_1st rows
#define ROWS2 (NB * NM * 4)   // 800000 x_2nd/out rows

typedef __attribute__((ext_vector_type(4))) float f32x4;
typedef __attribute__((ext_vector_type(8))) short s16x8;   // 8 bf16 (4 VGPRs) MFMA frag

// fp32 -> bf16 round-to-nearest-even (data is well-behaved normals; no NaN path)
static __device__ __forceinline__ unsigned short f2bf(float f) {
    union { float f; unsigned int u; } v; v.f = f;
    unsigned int u = v.u;
    u += 0x7fffu + ((u >> 16) & 1u);
    return (unsigned short)(u >> 16);
}

static __device__ __forceinline__ s16x8 pack8(f32x4 a, f32x4 b) {
    s16x8 r;
    r[0] = (short)f2bf(a[0]); r[1] = (short)f2bf(a[1]);
    r[2] = (short)f2bf(a[2]); r[3] = (short)f2bf(a[3]);
    r[4] = (short)f2bf(b[0]); r[5] = (short)f2bf(b[1]);
    r[6] = (short)f2bf(b[2]); r[7] = (short)f2bf(b[3]);
    return r;
}

// ---------------------------------------------------------------------------
// k0: Wc = We·Wm (bf16), We -> bf16, bc = We·bm + be (fp32).
// 16 blocks x 256 threads: thread g computes Wc[g>>6][g&63].
// We row is wave-uniform (scalar loads); Wm column access is lane-coalesced.
// ---------------------------------------------------------------------------
__global__ __launch_bounds__(256) void k0_prep(const float* __restrict__ Wm,
                        const float* __restrict__ bm,
                        const float* __restrict__ We, const float* __restrict__ be,
                        float* __restrict__ bc,
                        unsigned short* __restrict__ Wc_bf,
                        unsigned short* __restrict__ We_bf) {
    const int g = blockIdx.x * 256 + threadIdx.x;   // 0..4095
    const int o = g >> 6;
    const int d = g & 63;
    const float* wrow = We + o * 64;
    float acc = 0.f;
#pragma unroll 8
    for (int e = 0; e < 64; ++e) acc += wrow[e] * Wm[e * 64 + d];
    Wc_bf[g] = f2bf(acc);
    We_bf[g] = f2bf(We[g]);
    if (g < 64) {
        float a2 = be[g];
#pragma unroll 8
        for (int e = 0; e < 64; ++e) a2 += We[g * 64 + e] * bm[e];
        bc[g] = a2;
    }
}

// ---------------------------------------------------------------------------
// k1: G[row] = Wc·x1[row] + 0.5*bc   for the 40000 x_1st rows.
// One wave per 16 rows. MFMA 16x16x32 bf16: A=Wc tile, B=x1 rows.
// ---------------------------------------------------------------------------
__global__ __launch_bounds__(256) void k1_G(const float* __restrict__ x1,
        const unsigned short* __restrict__ Wc_bf, const float* __restrict__ bc,
        float* __restrict__ G) {
    const int lane = threadIdx.x & 63;
    const int wt = blockIdx.x * 4 + (threadIdx.x >> 6);
    const int rowbase = wt * 16;
    const int i = lane & 15;    // A-row (o within 16-tile) AND B-col (x1 row within tile)
    const int kg = lane >> 4;   // k-group

    // B fragments: x1 rows, k = kh*32 + kg*8 + {0..7}
    const float* xr = x1 + (size_t)(rowbase + i) * 64 + kg * 8;
    const s16x8 b0 = pack8(*(const f32x4*)(xr),      *(const f32x4*)(xr + 4));
    const s16x8 b1 = pack8(*(const f32x4*)(xr + 32), *(const f32x4*)(xr + 36));

    f32x4 acc[4];
#pragma unroll
    for (int t = 0; t < 4; ++t) acc[t] = (f32x4){0.f, 0.f, 0.f, 0.f};

#pragma unroll
    for (int t = 0; t < 4; ++t) {
        const unsigned short* wr = Wc_bf + (t * 16 + i) * 64 + kg * 8;
        const s16x8 a0 = *(const s16x8*)(wr);
        const s16x8 a1 = *(const s16x8*)(wr + 32);
        acc[t] = __builtin_amdgcn_mfma_f32_16x16x32_bf16(a0, b0, acc[t], 0, 0, 0);
        acc[t] = __builtin_amdgcn_mfma_f32_16x16x32_bf16(a1, b1, acc[t], 0, 0, 0);
    }

    // D layout: col=lane&15 (row of x1), row=(lane>>4)*4+reg (output o within tile)
    float* grow = G + (size_t)(rowbase + i) * 64;
#pragma unroll
    for (int t = 0; t < 4; ++t) {
        const int o = t * 16 + kg * 4;
        const f32x4 bcv = *(const f32x4*)(bc + o);
        f32x4 v;
#pragma unroll
        for (int r = 0; r < 4; ++r) v[r] = acc[t][r] + 0.5f * bcv[r];
        *(f32x4*)(grow + o) = v;
    }
}

// ---------------------------------------------------------------------------
// k2: out[row] = We·x2[row] + G[b,e0,I(c)] + G[b,e1,J(c)]   (bias inside G)
// One wave per 16 rows (= 4 edges x 4 channels). 8 MFMA per wave.
// ---------------------------------------------------------------------------
__global__ __launch_bounds__(256) void k2_main(const float* __restrict__ x2,
        const unsigned short* __restrict__ We_bf, const int* __restrict__ edge,
        const float* __restrict__ G, float* __restrict__ out) {
    const int lane = threadIdx.x & 63;
    const int wt = blockIdx.x * 4 + (threadIdx.x >> 6);
    const unsigned int rowbase = (unsigned int)wt * 16u;
    const int i = lane & 15;
    const int kg = lane >> 4;

    // A fragments: We tiles (bf16, pre-converted; L1-hot)
    s16x8 a[4][2];
#pragma unroll
    for (int t = 0; t < 4; ++t) {
        const unsigned short* wr = We_bf + (t * 16 + i) * 64 + kg * 8;
        a[t][0] = *(const s16x8*)(wr);
        a[t][1] = *(const s16x8*)(wr + 32);
    }

    // B fragments: 16 rows of x2
    const float* xr = x2 + (size_t)(rowbase + i) * 64 + kg * 8;
    const s16x8 b0 = pack8(*(const f32x4*)(xr),      *(const f32x4*)(xr + 4));
    const s16x8 b1 = pack8(*(const f32x4*)(xr + 32), *(const f32x4*)(xr + 36));

    f32x4 acc[4];
#pragma unroll
    for (int t = 0; t < 4; ++t) acc[t] = (f32x4){0.f, 0.f, 0.f, 0.f};
#pragma unroll
    for (int t = 0; t < 4; ++t) {
        acc[t] = __builtin_amdgcn_mfma_f32_16x16x32_bf16(a[t][0], b0, acc[t], 0, 0, 0);
        acc[t] = __builtin_amdgcn_mfma_f32_16x16x32_bf16(a[t][1], b1, acc[t], 0, 0, 0);
    }

    // Epilogue: each lane owns one full output row (gr), o-slices of 4 per tile t.
    const unsigned int gr = rowbase + (unsigned int)i;   // global row in (B,M,4), < 800000
    const int b = (gr >= (unsigned int)(NM * 4)) ? 1 : 0;
    const unsigned int mc = gr - (unsigned int)b * (NM * 4u);
    const unsigned int m = mc >> 2;
    const unsigned int c = mc & 3u;                      // channel: I=c>>1, J=c&1
    const int e0 = edge[m];
    const int e1 = edge[NM + m];
    const float* Gi = G + (((size_t)b * NT + e0) * 2 + (c >> 1)) * 64;
    const float* Gj = G + (((size_t)b * NT + e1) * 2 + (c & 1)) * 64;
    float* orow = out + (size_t)gr * 64;
#pragma unroll
    for (int t = 0; t < 4; ++t) {
        const int o = t * 16 + kg * 4;
        const f32x4 gi = *(const f32x4*)(Gi + o);
        const f32x4 gj = *(const f32x4*)(Gj + o);
        f32x4 v;
#pragma unroll
        for (int r = 0; r < 4; ++r) v[r] = acc[t][r] + gi[r] + gj[r];
        __builtin_nontemporal_store(v, (f32x4*)(orow + o));
    }
}

// ---------------------------------------------------------------------------
extern "C" void kernel_launch(void* const* d_in, const int* in_sizes, int n_in,
                              void* d_out, int out_size, void* d_ws, size_t ws_size,
                              hipStream_t stream) {
    const float* x1 = (const float*)d_in[0];   // (B,T,2,D)
    const float* x2 = (const float*)d_in[1];   // (B,M,4,D)
    const float* Wm = (const float*)d_in[2];   // (D,D)
    const float* bm = (const float*)d_in[3];   // (D,)
    const float* We = (const float*)d_in[4];   // (D,D)
    const float* be = (const float*)d_in[5];   // (D,)
    const int* edge = (const int*)d_in[6];     // (2,M)
    float* out = (float*)d_out;

    // Workspace layout: G (40000*64 f32) | bc (64 f32) | Wc_bf (4096 u16) | We_bf (4096 u16)
    float* G = (float*)d_ws;
    float* bc = G + (size_t)ROWS1 * 64;                      // offset 2,560,000 floats
    unsigned short* Wc_bf = (unsigned short*)(bc + 64);      // 16B-aligned
    unsigned short* We_bf = Wc_bf + 64 * 64;

    k0_prep<<<16, 256, 0, stream>>>(Wm, bm, We, be, bc, Wc_bf, We_bf);
    k1_G<<<ROWS1 / 16 / 4, 256, 0, stream>>>(x1, Wc_bf, bc, G);        // 625 blocks
    k2_main<<<ROWS2 / 16 / 4, 256, 0, stream>>>(x2, We_bf, edge, G, out); // 12500 blocks
}